// Round 8
// baseline (166.343 us; speedup 1.0000x reference)
//
#include <hip/hip_runtime.h>
#include <hip/hip_fp16.h>

// ---------- types ----------
typedef __attribute__((ext_vector_type(8))) _Float16 f16x8;
typedef __attribute__((ext_vector_type(4))) float f32x4;

typedef const __attribute__((address_space(1))) void gas_void;
typedef __attribute__((address_space(3))) void las_void;
typedef __attribute__((address_space(3))) const __half las_chalf;

// asm ds_read_b128: opaque to the compiler's waitcnt pass (we manage lgkmcnt)
__device__ __forceinline__ f16x8 ldsr(const __half* p) {
    f16x8 r;
    asm volatile("ds_read_b128 %0, %1" : "=v"(r) : "v"((las_chalf*)p));
    return r;
}

// ---------- all input casts f32 -> f16 in one dispatch (grid 3584) ----------
__global__ __launch_bounds__(256) void cast_all_k(const float* __restrict__ x,
                                                  const float* __restrict__ wq,
                                                  const float* __restrict__ wk,
                                                  const float* __restrict__ wv,
                                                  __half* __restrict__ xb,
                                                  __half* __restrict__ wqkv) {
    const int b = blockIdx.x;
    const float* src;
    __half* dst;
    size_t i;
    if (b < 2048) {
        src = x; dst = xb;
        i = ((size_t)b * 256 + threadIdx.x) * 8;
    } else {
        const int w = (b - 2048) >> 9;
        src = w == 0 ? wq : (w == 1 ? wk : wv);
        dst = wqkv + (size_t)w * 1048576;
        i = (((size_t)((b - 2048) & 511)) * 256 + threadIdx.x) * 8;
    }
    float4 a = *(const float4*)(src + i);
    float4 c = *(const float4*)(src + i + 4);
    __half2 h[4] = { __floats2half2_rn(a.x, a.y), __floats2half2_rn(a.z, a.w),
                     __floats2half2_rn(c.x, c.y), __floats2half2_rn(c.z, c.w) };
    *(int4*)(dst + i) = *(int4*)h;
}

// ---------- transpose [R][C] (row stride ldin) -> [C][R] (f16) ----------
__global__ __launch_bounds__(256) void transpose_f16_k(const __half* __restrict__ in,
                                                       __half* __restrict__ out,
                                                       int R, int ldin) {
    __shared__ __half t[64][72];
    int r0 = blockIdx.x * 64, c0 = blockIdx.y * 64;
    for (int idx = threadIdx.x; idx < 64 * 64; idx += 256) {
        int r = idx >> 6, c = idx & 63;
        t[r][c] = in[(size_t)(r0 + r) * ldin + c0 + c];
    }
    __syncthreads();
    for (int idx = threadIdx.x; idx < 64 * 64; idx += 256) {
        int r = idx >> 6, c = idx & 63;
        out[(size_t)(c0 + r) * R + r0 + c] = t[c][r];
    }
}

__device__ __forceinline__ void storeC(__half* C, size_t off, float v) { C[off] = __float2half(v); }
__device__ __forceinline__ void storeC(float*  C, size_t off, float v) { C[off] = v; }

// ============================================================================
// 256x256 8-phase GEMM (T2+T3+T4+T5), C = scale * A @ B^T (NT layout, f16).
// 8 waves (2M x 4N), BK=64, LDS 128KB dynamic: [buf(2)][mat(2)][256][64] f16.
// SPLITK: balanced causal split-K for PV (chunk 0 -> C, 1..3 -> P1..P3).
// STATS : per-row (max, sum-exp) partials into Mp/Lp[row][16] (diag-masked).
// ============================================================================
template <typename CT, bool LOWER_ONLY, bool SPLITK, bool STATS>
__global__ __launch_bounds__(512, 2)
void gemm256(const __half* __restrict__ A, const __half* __restrict__ B, CT* __restrict__ C,
             float* __restrict__ P1, float* __restrict__ P2, float* __restrict__ P3,
             float* __restrict__ Mp, float* __restrict__ Lp,
             int lda, int ldb, int ldc, int NTin, float scale) {
    int bi, c = 0;
    const int bj = blockIdx.y;
    if (SPLITK) {
        int x = blockIdx.x;
        if (x < 4)       { bi = x;                    c = 0; }
        else if (x < 12) { bi = 4  + ((x - 4) >> 1);  c = (x - 4) & 1; }
        else if (x < 24) { bi = 8  + (x - 12) / 3;    c = (x - 12) % 3; }
        else             { bi = 12 + ((x - 24) >> 2); c = (x - 24) & 3; }
    } else {
        bi = blockIdx.x;
        if (LOWER_ONLY && bj > bi) return;
    }
    const int brow = bi * 256, bcol = bj * 256;
    const int tid = threadIdx.x;
    const int lane = tid & 63, wid = tid >> 6;
    const int wm = wid >> 2, wn = wid & 3;
    const int lane15 = lane & 15;
    const int kxor = (lane & 7) << 3;
    const int g16 = (lane >> 4) << 3;

    int k_lo = 0, NT = NTin;
    if (SPLITK) { int full = 4 * (bi + 1); k_lo = c * 16; NT = min(full - k_lo, 16); }

    extern __shared__ __half smem[];  // [2][2][256*64]

    const int srow = (wid << 3) + (lane >> 3);                 // 0..63
    const int scol = ((lane & 7) ^ ((lane >> 3) & 7)) << 3;    // swizzled source col

    auto stage_half = [&](const __half* G, int ldg, int growbase, int kt, int buf, int mat, int half) {
        const __half* src = G + (size_t)(growbase + half * 128 + srow) * ldg + kt * 64 + scol;
        __half* dst = &smem[buf * 32768 + mat * 16384 + (half * 128 + (wid << 3)) * 64];
        __builtin_amdgcn_global_load_lds((gas_void*)src, (las_void*)dst, 16, 0, 0);
        __builtin_amdgcn_global_load_lds((gas_void*)(src + (size_t)64 * ldg),
                                         (las_void*)(dst + 64 * 64), 16, 0, 0);
    };

    f32x4 acc[8][4] = {};
    f16x8 bfrag[2][4];

    // prologue: tile k_lo {Ba,Bb,Aa,Ab} + tile k_lo+1 {Ba,Bb}
    stage_half(B, ldb, bcol, k_lo, 0, 1, 0);
    stage_half(B, ldb, bcol, k_lo, 0, 1, 1);
    stage_half(A, lda, brow, k_lo, 0, 0, 0);
    stage_half(A, lda, brow, k_lo, 0, 0, 1);
    if (NT > 1) {
        stage_half(B, ldb, bcol, k_lo + 1, 1, 1, 0);
        stage_half(B, ldb, bcol, k_lo + 1, 1, 1, 1);
    }

    for (int Tr = 0; Tr < NT; ++Tr) {
        const int Ta = k_lo + Tr;
        const int buf = Tr & 1;
        const __half* Abase = &smem[buf * 32768 + (wm * 128 + lane15) * 64];
        const __half* Bbase = &smem[buf * 32768 + 16384 + (wn * 64 + lane15) * 64];

        // ---- phase 0 ----
        if (Tr < NT - 1) asm volatile("s_waitcnt vmcnt(4)" ::: "memory");
        else             asm volatile("s_waitcnt vmcnt(0)" ::: "memory");
        __builtin_amdgcn_s_barrier();   // tile Tr fully resident for all waves

        {
#pragma unroll
            for (int kk = 0; kk < 2; ++kk)
#pragma unroll
                for (int n = 0; n < 4; ++n)
                    bfrag[kk][n] = ldsr(Bbase + (n * 16) * 64 + ((kk * 32 + g16) ^ kxor));
            f16x8 af[2][2];
#pragma unroll
            for (int mi = 0; mi < 2; ++mi)
#pragma unroll
                for (int kk = 0; kk < 2; ++kk)
                    af[mi][kk] = ldsr(Abase + (mi * 16) * 64 + ((kk * 32 + g16) ^ kxor));
            if (Tr + 1 < NT) stage_half(A, lda, brow, Ta + 1, buf ^ 1, 0, 0);
            asm volatile("s_waitcnt lgkmcnt(0)" ::: "memory");
            __builtin_amdgcn_sched_barrier(0);
            __builtin_amdgcn_s_setprio(1);
#pragma unroll
            for (int mi = 0; mi < 2; ++mi)
#pragma unroll
                for (int n = 0; n < 4; ++n)
#pragma unroll
                    for (int kk = 0; kk < 2; ++kk)
                        acc[mi][n] = __builtin_amdgcn_mfma_f32_16x16x32_f16(
                            af[mi][kk], bfrag[kk][n], acc[mi][n], 0, 0, 0);
            __builtin_amdgcn_s_setprio(0);
            __builtin_amdgcn_s_barrier();
        }

        // ---- phases 1..3 ----
#pragma unroll
        for (int p = 1; p < 4; ++p) {
            f16x8 af[2][2];
#pragma unroll
            for (int mi = 0; mi < 2; ++mi)
#pragma unroll
                for (int kk = 0; kk < 2; ++kk)
                    af[mi][kk] = ldsr(Abase + ((2 * p + mi) * 16) * 64 + ((kk * 32 + g16) ^ kxor));
            if (p == 1)      { if (Tr + 1 < NT) stage_half(A, lda, brow, Ta + 1, buf ^ 1, 0, 1); }
            else if (p == 2) { if (Tr + 2 < NT) stage_half(B, ldb, bcol, Ta + 2, buf, 1, 0); }
            else             { if (Tr + 2 < NT) stage_half(B, ldb, bcol, Ta + 2, buf, 1, 1); }
            asm volatile("s_waitcnt lgkmcnt(0)" ::: "memory");
            __builtin_amdgcn_sched_barrier(0);
            __builtin_amdgcn_s_setprio(1);
#pragma unroll
            for (int mi = 0; mi < 2; ++mi)
#pragma unroll
                for (int n = 0; n < 4; ++n)
#pragma unroll
                    for (int kk = 0; kk < 2; ++kk)
                        acc[2 * p + mi][n] = __builtin_amdgcn_mfma_f32_16x16x32_f16(
                            af[mi][kk], bfrag[kk][n], acc[2 * p + mi][n], 0, 0, 0);
            __builtin_amdgcn_s_setprio(0);
            __builtin_amdgcn_s_barrier();
        }
    }

    // ---- row stats (S only): per-row max & sum-exp over this block's 256 cols ----
    if (STATS) {
        const bool diag = (bi == bj);
        __syncthreads();                       // LDS reads all done; reuse smem
        float* sst = (float*)smem;             // [256 rows][4 wn][2]
        const int g4 = lane >> 4;
#pragma unroll
        for (int m = 0; m < 8; ++m) {
#pragma unroll
            for (int r = 0; r < 4; ++r) {
                const int lrow = wm * 128 + m * 16 + g4 * 4 + r;
                const int grow = brow + lrow;
                float v[4];
                bool ok[4];
                float mx = -1e30f;
#pragma unroll
                for (int n = 0; n < 4; ++n) {
                    const int gcol = bcol + wn * 64 + n * 16 + lane15;
                    v[n] = acc[m][n][r] * scale;
                    ok[n] = (!diag) || (gcol <= grow);
                    if (ok[n]) mx = fmaxf(mx, v[n]);
                }
#pragma unroll
                for (int off = 1; off < 16; off <<= 1) mx = fmaxf(mx, __shfl_xor(mx, off));
                float sm = 0.f;
#pragma unroll
                for (int n = 0; n < 4; ++n) if (ok[n]) sm += __expf(v[n] - mx);
#pragma unroll
                for (int off = 1; off < 16; off <<= 1) sm += __shfl_xor(sm, off);
                if (lane15 == 0) {
                    sst[(lrow * 4 + wn) * 2 + 0] = mx;
                    sst[(lrow * 4 + wn) * 2 + 1] = sm;
                }
            }
        }
        __syncthreads();
        if (tid < 256) {
            float M2 = -1e30f, L2 = 0.f;
#pragma unroll
            for (int w = 0; w < 4; ++w) {
                float m2 = sst[(tid * 4 + w) * 2 + 0];
                float s2 = sst[(tid * 4 + w) * 2 + 1];
                float nm2 = fmaxf(M2, m2);
                L2 = L2 * __expf(M2 - nm2) + s2 * __expf(m2 - nm2);
                M2 = nm2;
            }
            Mp[(size_t)(brow + tid) * 16 + bj] = M2;
            Lp[(size_t)(brow + tid) * 16 + bj] = L2;
        }
    }

    // ---- epilogue ----
    CT* Ct = C;
    if (SPLITK && c > 0) Ct = (CT*)(c == 1 ? P1 : (c == 2 ? P2 : P3));
    const int r0 = (lane >> 4) << 2;
#pragma unroll
    for (int m = 0; m < 8; ++m) {
#pragma unroll
        for (int n = 0; n < 4; ++n) {
            int col = bcol + wn * 64 + n * 16 + lane15;
#pragma unroll
            for (int r = 0; r < 4; ++r) {
                int row = brow + wm * 128 + m * 16 + r0 + r;
                storeC(Ct, (size_t)row * ldc + col, acc[m][n][r] * scale);
            }
        }
    }
}

// ---------- split-K reduce: out[row] += P1 (+P2 if row>=2048) (+P3 if row>=3072) ----------
__global__ __launch_bounds__(256) void pv_reduce_k(float* __restrict__ out,
                                                   const float* __restrict__ P1,
                                                   const float* __restrict__ P2,
                                                   const float* __restrict__ P3) {
    const int row = 1024 + blockIdx.x;
    const size_t o = (size_t)row * 1024 + threadIdx.x * 4;
    float4 s = *(float4*)(out + o);
    float4 a = *(const float4*)(P1 + o);
    s.x += a.x; s.y += a.y; s.z += a.z; s.w += a.w;
    if (row >= 2048) {
        float4 b = *(const float4*)(P2 + o);
        s.x += b.x; s.y += b.y; s.z += b.z; s.w += b.w;
    }
    if (row >= 3072) {
        float4 d = *(const float4*)(P3 + o);
        s.x += d.x; s.y += d.y; s.z += d.z; s.w += d.w;
    }
    *(float4*)(out + o) = s;
}

// ---------- threefry2x32, JAX PARTITIONABLE variant ----------
__device__ __forceinline__ uint32_t rotl32(uint32_t x, int d) { return (x << d) | (x >> (32 - d)); }

__device__ __forceinline__ bool keep_bit(uint32_t flat) {
    uint32_t x0 = 0u;
    uint32_t x1 = flat;
    const uint32_t ks0 = 0u, ks1 = 42u, ks2 = 0u ^ 42u ^ 0x1BD11BDAu;
    x0 += ks0; x1 += ks1;
#define TFR(r) { x0 += x1; x1 = rotl32(x1, r); x1 ^= x0; }
    TFR(13) TFR(15) TFR(26) TFR(6)   x0 += ks1; x1 += ks2 + 1u;
    TFR(17) TFR(29) TFR(16) TFR(24)  x0 += ks2; x1 += ks0 + 2u;
    TFR(13) TFR(15) TFR(26) TFR(6)   x0 += ks0; x1 += ks1 + 3u;
    TFR(17) TFR(29) TFR(16) TFR(24)  x0 += ks1; x1 += ks2 + 4u;
    TFR(13) TFR(15) TFR(26) TFR(6)   x0 += ks2; x1 += ks0 + 5u;
#undef TFR
    uint32_t bits = x0 ^ x1;
    float u = __uint_as_float((bits >> 9) | 0x3f800000u) - 1.0f;
    return u < 0.9f;
}

// ---------- single-pass softmax + dropout using precomputed row partials ----------
__global__ __launch_bounds__(256) void softmax_dropout_k(__half* __restrict__ SP,
                                                         const float* __restrict__ Mp,
                                                         const float* __restrict__ Lp,
                                                         int N) {
    const int i = blockIdx.x;
    const int tid = threadIdx.x;
    const int len = i + 1;
    __half* row = SP + (size_t)i * N;

    // merge <=16 per-block partials (same math as online softmax merge)
    const int nb = (i >> 8) + 1;
    float M = -1e30f;
    for (int b = 0; b < nb; ++b) M = fmaxf(M, Mp[(size_t)i * 16 + b]);
    float L = 0.f;
    for (int b = 0; b < nb; ++b) L += Lp[(size_t)i * 16 + b] * __expf(Mp[(size_t)i * 16 + b] - M);
    const float inv = 1.0f / (L * 0.9f);

    // single sweep: 8-wide load, 8 independent threefry chains, 8-wide store
    const int len8 = len & ~7;
    for (int j = tid * 8; j < len8; j += 2048) {
        int4 pk = *(const int4*)(row + j);
        const __half* hp = (const __half*)&pk;
        __half o8[8];
        const uint32_t base = (uint32_t)i * 4096u + (uint32_t)j;
#pragma unroll
        for (int q = 0; q < 8; ++q) {
            float w = __expf(__half2float(hp[q]) - M) * inv;
            o8[q] = keep_bit(base + q) ? __float2half(w) : __float2half(0.0f);
        }
        *(int4*)(row + j) = *(int4*)o8;
    }
    for (int j = len8 + tid; j < len; j += 256) {
        float w = __expf(__half2float(row[j]) - M) * inv;
        row[j] = keep_bit((uint32_t)i * 4096u + (uint32_t)j) ? __float2half(w) : __float2half(0.0f);
    }

    // zero the diagonal band up to the next 256 boundary (PV K-tiles are 256 wide)
    const int zlim = ((i >> 8) << 8) + 256;
    const int za = (len + 7) & ~7;
    for (int j = len + tid; j < min(za, zlim); j += 256) row[j] = __float2half(0.0f);
    const int4 z = {0, 0, 0, 0};
    for (int j = za + tid * 8; j < zlim; j += 2048) *(int4*)(row + j) = z;
}

// ---------- launch ----------
extern "C" void kernel_launch(void* const* d_in, const int* in_sizes, int n_in,
                              void* d_out, int out_size, void* d_ws, size_t ws_size,
                              hipStream_t stream) {
    const float* x  = (const float*)d_in[0];
    const float* wq = (const float*)d_in[1];
    const float* wk = (const float*)d_in[2];
    const float* wv = (const float*)d_in[3];
    float* out = (float*)d_out;
    char* ws = (char*)d_ws;

    const int N = 4096, D = 1024;

    __half* xb   = (__half*)(ws + 0);         // 4096x1024   (8 MB)
    __half* wqkv = (__half*)(ws + 8388608);   // 3072x1024   (6 MB)
    __half* QKV  = (__half*)(ws + 14680064);  // 4096x3072   (24 MB), ld=3072
    __half* VT   = (__half*)(ws + 39845888);  // 1024x4096   (8 MB)
    __half* SP   = (__half*)(ws + 48234496);  // 4096x4096   (32 MB), end 81788928
    float*  Mp   = (float*)(ws + 81788928);   // 4096x16 f32 (256 KB)
    float*  Lp   = (float*)(ws + 82051072);   // 4096x16 f32 (256 KB), end 82313216

    // split-K partials overlay the (dead-by-then) QKV region
    float* P1 = (float*)(ws + 14680064) - (size_t)1024 * 1024;
    float* P2 = (float*)(ws + 14680064 + 12582912) - (size_t)2048 * 1024;
    float* P3 = (float*)(ws + 14680064 + 20971520) - (size_t)3072 * 1024;

    __half* Q = QKV;            // lda = 3072
    __half* K = QKV + 1024;
    __half* V = QKV + 2048;

    auto* gqkv_f = gemm256<__half, false, false, false>;
    auto* gs_f   = gemm256<__half, true,  false, true>;
    auto* gpv_f  = gemm256<float,  false, true,  false>;
    (void)hipFuncSetAttribute((const void*)gqkv_f, hipFuncAttributeMaxDynamicSharedMemorySize, 131072);
    (void)hipFuncSetAttribute((const void*)gs_f,   hipFuncAttributeMaxDynamicSharedMemorySize, 131072);
    (void)hipFuncSetAttribute((const void*)gpv_f,  hipFuncAttributeMaxDynamicSharedMemorySize, 131072);

    cast_all_k<<<3584, 256, 0, stream>>>(x, wq, wk, wv, xb, wqkv);

    // fused QKV projection: [4096x1024] @ [3072x1024]^T -> [4096x3072]
    dim3 gq(N / 256, 3 * D / 256);   // 16 x 12
    gqkv_f<<<gq, 512, 131072, stream>>>(xb, wqkv, QKV, nullptr, nullptr, nullptr,
                                        nullptr, nullptr, D, D, 3 * D, D / 64, 1.0f);

    dim3 gt(N / 64, D / 64);
    transpose_f16_k<<<gt, 256, 0, stream>>>(V, VT, N, 3 * D);

    // S = Q @ K^T * (1/32), lower-triangle blocks only, + row stats
    dim3 gsd(N / 256, N / 256);      // 16 x 16, bj>bi early-out
    gs_f<<<gsd, 512, 131072, stream>>>(Q, K, SP, nullptr, nullptr, nullptr,
                                       Mp, Lp, 3 * D, 3 * D, N, D / 64, 0.03125f);

    softmax_dropout_k<<<N, 256, 0, stream>>>(SP, Mp, Lp, N);

    // PV on the 8-phase engine: balanced causal split-K (chunks of <=16 BK-tiles)
    dim3 go(40, D / 256);            // 160 blocks
    gpv_f<<<go, 512, 131072, stream>>>(SP, VT, out, P1, P2, P3,
                                       nullptr, nullptr, N, N, D, 0, 1.0f);
    pv_reduce_k<<<3072, 256, 0, stream>>>(out, P1, P2, P3);
}

// Round 9
// 151.553 us; speedup vs baseline: 1.0976x; 1.0976x over previous
//
#include <hip/hip_runtime.h>
#include <hip/hip_fp16.h>

// ---------- types ----------
typedef __attribute__((ext_vector_type(8))) _Float16 f16x8;
typedef __attribute__((ext_vector_type(4))) float f32x4;

typedef const __attribute__((address_space(1))) void gas_void;
typedef __attribute__((address_space(3))) void las_void;
typedef __attribute__((address_space(3))) const __half las_chalf;

// asm ds_read_b128: opaque to the compiler's waitcnt pass (we manage lgkmcnt)
__device__ __forceinline__ f16x8 ldsr(const __half* p) {
    f16x8 r;
    asm volatile("ds_read_b128 %0, %1" : "=v"(r) : "v"((las_chalf*)p));
    return r;
}

// ---------- all input casts f32 -> f16 in one dispatch (grid 3584) ----------
__global__ __launch_bounds__(256) void cast_all_k(const float* __restrict__ x,
                                                  const float* __restrict__ wq,
                                                  const float* __restrict__ wk,
                                                  const float* __restrict__ wv,
                                                  __half* __restrict__ xb,
                                                  __half* __restrict__ wqkv) {
    const int b = blockIdx.x;
    const float* src;
    __half* dst;
    size_t i;
    if (b < 2048) {
        src = x; dst = xb;
        i = ((size_t)b * 256 + threadIdx.x) * 8;
    } else {
        const int w = (b - 2048) >> 9;
        src = w == 0 ? wq : (w == 1 ? wk : wv);
        dst = wqkv + (size_t)w * 1048576;
        i = (((size_t)((b - 2048) & 511)) * 256 + threadIdx.x) * 8;
    }
    float4 a = *(const float4*)(src + i);
    float4 c = *(const float4*)(src + i + 4);
    __half2 h[4] = { __floats2half2_rn(a.x, a.y), __floats2half2_rn(a.z, a.w),
                     __floats2half2_rn(c.x, c.y), __floats2half2_rn(c.z, c.w) };
    *(int4*)(dst + i) = *(int4*)h;
}

// ---------- transpose [R][C] (row stride ldin) -> [C][R] (f16) ----------
__global__ __launch_bounds__(256) void transpose_f16_k(const __half* __restrict__ in,
                                                       __half* __restrict__ out,
                                                       int R, int ldin) {
    __shared__ __half t[64][72];
    int r0 = blockIdx.x * 64, c0 = blockIdx.y * 64;
    for (int idx = threadIdx.x; idx < 64 * 64; idx += 256) {
        int r = idx >> 6, c = idx & 63;
        t[r][c] = in[(size_t)(r0 + r) * ldin + c0 + c];
    }
    __syncthreads();
    for (int idx = threadIdx.x; idx < 64 * 64; idx += 256) {
        int r = idx >> 6, c = idx & 63;
        out[(size_t)(c0 + r) * R + r0 + c] = t[c][r];
    }
}

__device__ __forceinline__ void storeC(__half* C, size_t off, float v) { C[off] = __float2half(v); }
__device__ __forceinline__ void storeC(float*  C, size_t off, float v) { C[off] = v; }

// ============================================================================
// 256x256 8-phase GEMM (T2+T3+T4+T5), C = scale * A @ B^T (NT layout, f16).
// 8 waves (2M x 4N), BK=64, LDS 128KB dynamic: [buf(2)][mat(2)][256][64] f16.
// SPLITK: balanced causal split-K for PV (chunk 0 -> C, 1..3 -> P1..P3).
// ============================================================================
template <typename CT, bool LOWER_ONLY, bool SPLITK>
__global__ __launch_bounds__(512, 2)
void gemm256(const __half* __restrict__ A, const __half* __restrict__ B, CT* __restrict__ C,
             float* __restrict__ P1, float* __restrict__ P2, float* __restrict__ P3,
             int lda, int ldb, int ldc, int NTin, float scale) {
    int bi, c = 0;
    const int bj = blockIdx.y;
    if (SPLITK) {
        int x = blockIdx.x;
        if (x < 4)       { bi = x;                    c = 0; }
        else if (x < 12) { bi = 4  + ((x - 4) >> 1);  c = (x - 4) & 1; }
        else if (x < 24) { bi = 8  + (x - 12) / 3;    c = (x - 12) % 3; }
        else             { bi = 12 + ((x - 24) >> 2); c = (x - 24) & 3; }
    } else {
        bi = blockIdx.x;
        if (LOWER_ONLY && bj > bi) return;
    }
    const int brow = bi * 256, bcol = bj * 256;
    const int tid = threadIdx.x;
    const int lane = tid & 63, wid = tid >> 6;
    const int wm = wid >> 2, wn = wid & 3;
    const int lane15 = lane & 15;
    const int kxor = (lane & 7) << 3;
    const int g16 = (lane >> 4) << 3;

    int k_lo = 0, NT = NTin;
    if (SPLITK) { int full = 4 * (bi + 1); k_lo = c * 16; NT = min(full - k_lo, 16); }

    extern __shared__ __half smem[];  // [2][2][256*64]

    const int srow = (wid << 3) + (lane >> 3);                 // 0..63
    const int scol = ((lane & 7) ^ ((lane >> 3) & 7)) << 3;    // swizzled source col

    auto stage_half = [&](const __half* G, int ldg, int growbase, int kt, int buf, int mat, int half) {
        const __half* src = G + (size_t)(growbase + half * 128 + srow) * ldg + kt * 64 + scol;
        __half* dst = &smem[buf * 32768 + mat * 16384 + (half * 128 + (wid << 3)) * 64];
        __builtin_amdgcn_global_load_lds((gas_void*)src, (las_void*)dst, 16, 0, 0);
        __builtin_amdgcn_global_load_lds((gas_void*)(src + (size_t)64 * ldg),
                                         (las_void*)(dst + 64 * 64), 16, 0, 0);
    };

    f32x4 acc[8][4] = {};
    f16x8 bfrag[2][4];

    // prologue: tile k_lo {Ba,Bb,Aa,Ab} + tile k_lo+1 {Ba,Bb}
    stage_half(B, ldb, bcol, k_lo, 0, 1, 0);
    stage_half(B, ldb, bcol, k_lo, 0, 1, 1);
    stage_half(A, lda, brow, k_lo, 0, 0, 0);
    stage_half(A, lda, brow, k_lo, 0, 0, 1);
    if (NT > 1) {
        stage_half(B, ldb, bcol, k_lo + 1, 1, 1, 0);
        stage_half(B, ldb, bcol, k_lo + 1, 1, 1, 1);
    }

    for (int Tr = 0; Tr < NT; ++Tr) {
        const int Ta = k_lo + Tr;
        const int buf = Tr & 1;
        const __half* Abase = &smem[buf * 32768 + (wm * 128 + lane15) * 64];
        const __half* Bbase = &smem[buf * 32768 + 16384 + (wn * 64 + lane15) * 64];

        // ---- phase 0 ----
        if (Tr < NT - 1) asm volatile("s_waitcnt vmcnt(4)" ::: "memory");
        else             asm volatile("s_waitcnt vmcnt(0)" ::: "memory");
        __builtin_amdgcn_s_barrier();   // tile Tr fully resident for all waves

        {
#pragma unroll
            for (int kk = 0; kk < 2; ++kk)
#pragma unroll
                for (int n = 0; n < 4; ++n)
                    bfrag[kk][n] = ldsr(Bbase + (n * 16) * 64 + ((kk * 32 + g16) ^ kxor));
            f16x8 af[2][2];
#pragma unroll
            for (int mi = 0; mi < 2; ++mi)
#pragma unroll
                for (int kk = 0; kk < 2; ++kk)
                    af[mi][kk] = ldsr(Abase + (mi * 16) * 64 + ((kk * 32 + g16) ^ kxor));
            if (Tr + 1 < NT) stage_half(A, lda, brow, Ta + 1, buf ^ 1, 0, 0);
            asm volatile("s_waitcnt lgkmcnt(0)" ::: "memory");
            __builtin_amdgcn_sched_barrier(0);
            __builtin_amdgcn_s_setprio(1);
#pragma unroll
            for (int mi = 0; mi < 2; ++mi)
#pragma unroll
                for (int n = 0; n < 4; ++n)
#pragma unroll
                    for (int kk = 0; kk < 2; ++kk)
                        acc[mi][n] = __builtin_amdgcn_mfma_f32_16x16x32_f16(
                            af[mi][kk], bfrag[kk][n], acc[mi][n], 0, 0, 0);
            __builtin_amdgcn_s_setprio(0);
            __builtin_amdgcn_s_barrier();
        }

        // ---- phases 1..3 ----
#pragma unroll
        for (int p = 1; p < 4; ++p) {
            f16x8 af[2][2];
#pragma unroll
            for (int mi = 0; mi < 2; ++mi)
#pragma unroll
                for (int kk = 0; kk < 2; ++kk)
                    af[mi][kk] = ldsr(Abase + ((2 * p + mi) * 16) * 64 + ((kk * 32 + g16) ^ kxor));
            if (p == 1)      { if (Tr + 1 < NT) stage_half(A, lda, brow, Ta + 1, buf ^ 1, 0, 1); }
            else if (p == 2) { if (Tr + 2 < NT) stage_half(B, ldb, bcol, Ta + 2, buf, 1, 0); }
            else             { if (Tr + 2 < NT) stage_half(B, ldb, bcol, Ta + 2, buf, 1, 1); }
            asm volatile("s_waitcnt lgkmcnt(0)" ::: "memory");
            __builtin_amdgcn_sched_barrier(0);
            __builtin_amdgcn_s_setprio(1);
#pragma unroll
            for (int mi = 0; mi < 2; ++mi)
#pragma unroll
                for (int n = 0; n < 4; ++n)
#pragma unroll
                    for (int kk = 0; kk < 2; ++kk)
                        acc[2 * p + mi][n] = __builtin_amdgcn_mfma_f32_16x16x32_f16(
                            af[mi][kk], bfrag[kk][n], acc[2 * p + mi][n], 0, 0, 0);
            __builtin_amdgcn_s_setprio(0);
            __builtin_amdgcn_s_barrier();
        }
    }

    // ---- epilogue ----
    CT* Ct = C;
    if (SPLITK && c > 0) Ct = (CT*)(c == 1 ? P1 : (c == 2 ? P2 : P3));
    const int r0 = (lane >> 4) << 2;
#pragma unroll
    for (int m = 0; m < 8; ++m) {
#pragma unroll
        for (int n = 0; n < 4; ++n) {
            int col = bcol + wn * 64 + n * 16 + lane15;
#pragma unroll
            for (int r = 0; r < 4; ++r) {
                int row = brow + wm * 128 + m * 16 + r0 + r;
                storeC(Ct, (size_t)row * ldc + col, acc[m][n][r] * scale);
            }
        }
    }
}

// ---------- split-K merge + deferred softmax scaling: out = (out [+P..]) / (0.9*L) ----------
__global__ __launch_bounds__(256) void pv_scale_reduce_k(float* __restrict__ out,
                                                         const float* __restrict__ P1,
                                                         const float* __restrict__ P2,
                                                         const float* __restrict__ P3,
                                                         const float* __restrict__ L) {
    const int row = blockIdx.x;
    const float inv = 1.0f / (0.9f * L[row]);
    const size_t o = (size_t)row * 1024 + threadIdx.x * 4;
    float4 s = *(float4*)(out + o);
    if (row >= 1024) {
        float4 a = *(const float4*)(P1 + o);
        s.x += a.x; s.y += a.y; s.z += a.z; s.w += a.w;
    }
    if (row >= 2048) {
        float4 b = *(const float4*)(P2 + o);
        s.x += b.x; s.y += b.y; s.z += b.z; s.w += b.w;
    }
    if (row >= 3072) {
        float4 d = *(const float4*)(P3 + o);
        s.x += d.x; s.y += d.y; s.z += d.z; s.w += d.w;
    }
    s.x *= inv; s.y *= inv; s.z *= inv; s.w *= inv;
    *(float4*)(out + o) = s;
}

// ---------- threefry2x32, JAX PARTITIONABLE variant ----------
__device__ __forceinline__ uint32_t rotl32(uint32_t x, int d) { return (x << d) | (x >> (32 - d)); }

__device__ __forceinline__ bool keep_bit(uint32_t flat) {
    uint32_t x0 = 0u;
    uint32_t x1 = flat;
    const uint32_t ks0 = 0u, ks1 = 42u, ks2 = 0u ^ 42u ^ 0x1BD11BDAu;
    x0 += ks0; x1 += ks1;
#define TFR(r) { x0 += x1; x1 = rotl32(x1, r); x1 ^= x0; }
    TFR(13) TFR(15) TFR(26) TFR(6)   x0 += ks1; x1 += ks2 + 1u;
    TFR(17) TFR(29) TFR(16) TFR(24)  x0 += ks2; x1 += ks0 + 2u;
    TFR(13) TFR(15) TFR(26) TFR(6)   x0 += ks0; x1 += ks1 + 3u;
    TFR(17) TFR(29) TFR(16) TFR(24)  x0 += ks1; x1 += ks2 + 4u;
    TFR(13) TFR(15) TFR(26) TFR(6)   x0 += ks2; x1 += ks0 + 5u;
#undef TFR
    uint32_t bits = x0 ^ x1;
    float u = __uint_as_float((bits >> 9) | 0x3f800000u) - 1.0f;
    return u < 0.9f;
}

// ---------- single-sweep deferred softmax: P' = keep * exp(S) (M=0), L[row] = sum(exp) ----------
// Normalization 1/(0.9*L) is applied in pv_scale_reduce_k after PV.
// Safe: S = QK^T/32 ~ N(0,~1); f16 overflow needs S>11, harmful underflow needs
// row-max < -9.7 — both are >10-sigma events.
__global__ __launch_bounds__(256) void softdrop_k(__half* __restrict__ SP,
                                                  float* __restrict__ L, int N) {
    const int i = blockIdx.x;
    const int tid = threadIdx.x;
    const int len = i + 1;
    __half* row = SP + (size_t)i * N;

    float l = 0.f;
    const int len8 = len & ~7;
    for (int j = tid * 8; j < len8; j += 2048) {
        int4 pk = *(const int4*)(row + j);
        const __half* hp = (const __half*)&pk;
        __half o8[8];
        const uint32_t base = (uint32_t)i * 4096u + (uint32_t)j;
#pragma unroll
        for (int q = 0; q < 8; ++q) {
            float e = __expf(__half2float(hp[q]));
            l += e;
            o8[q] = keep_bit(base + q) ? __float2half(e) : __float2half(0.0f);
        }
        *(int4*)(row + j) = *(int4*)o8;
    }
    for (int j = len8 + tid; j < len; j += 256) {
        float e = __expf(__half2float(row[j]));
        l += e;
        row[j] = keep_bit((uint32_t)i * 4096u + (uint32_t)j) ? __float2half(e) : __float2half(0.0f);
    }

    // block-reduce l -> L[i]
    for (int off = 1; off < 64; off <<= 1) l += __shfl_xor(l, off);
    __shared__ float ls[4];
    if ((tid & 63) == 0) ls[tid >> 6] = l;
    __syncthreads();
    if (tid == 0) L[i] = ls[0] + ls[1] + ls[2] + ls[3];

    // zero the diagonal band up to the next 256 boundary (PV K-tiles are 256 wide)
    const int zlim = ((i >> 8) << 8) + 256;
    const int za = (len + 7) & ~7;
    for (int j = len + tid; j < min(za, zlim); j += 256) row[j] = __float2half(0.0f);
    const int4 z = {0, 0, 0, 0};
    for (int j = za + tid * 8; j < zlim; j += 2048) *(int4*)(row + j) = z;
}

// ---------- launch ----------
extern "C" void kernel_launch(void* const* d_in, const int* in_sizes, int n_in,
                              void* d_out, int out_size, void* d_ws, size_t ws_size,
                              hipStream_t stream) {
    const float* x  = (const float*)d_in[0];
    const float* wq = (const float*)d_in[1];
    const float* wk = (const float*)d_in[2];
    const float* wv = (const float*)d_in[3];
    float* out = (float*)d_out;
    char* ws = (char*)d_ws;

    const int N = 4096, D = 1024;

    __half* xb   = (__half*)(ws + 0);         // 4096x1024   (8 MB)
    __half* wqkv = (__half*)(ws + 8388608);   // 3072x1024   (6 MB)
    __half* QKV  = (__half*)(ws + 14680064);  // 4096x3072   (24 MB), ld=3072
    __half* VT   = (__half*)(ws + 39845888);  // 1024x4096   (8 MB)
    __half* SP   = (__half*)(ws + 48234496);  // 4096x4096   (32 MB), end 81788928
    float*  Lr   = (float*)(ws + 81788928);   // 4096 f32    (16 KB)

    // split-K partials overlay the (dead-by-then) QKV region
    float* P1 = (float*)(ws + 14680064) - (size_t)1024 * 1024;
    float* P2 = (float*)(ws + 14680064 + 12582912) - (size_t)2048 * 1024;
    float* P3 = (float*)(ws + 14680064 + 20971520) - (size_t)3072 * 1024;

    __half* Q = QKV;            // lda = 3072
    __half* K = QKV + 1024;
    __half* V = QKV + 2048;

    auto* gqkv_f = gemm256<__half, false, false>;
    auto* gs_f   = gemm256<__half, true,  false>;
    auto* gpv_f  = gemm256<float,  false, true>;
    (void)hipFuncSetAttribute((const void*)gqkv_f, hipFuncAttributeMaxDynamicSharedMemorySize, 131072);
    (void)hipFuncSetAttribute((const void*)gs_f,   hipFuncAttributeMaxDynamicSharedMemorySize, 131072);
    (void)hipFuncSetAttribute((const void*)gpv_f,  hipFuncAttributeMaxDynamicSharedMemorySize, 131072);

    cast_all_k<<<3584, 256, 0, stream>>>(x, wq, wk, wv, xb, wqkv);

    // fused QKV projection: [4096x1024] @ [3072x1024]^T -> [4096x3072]
    dim3 gq(N / 256, 3 * D / 256);   // 16 x 12
    gqkv_f<<<gq, 512, 131072, stream>>>(xb, wqkv, QKV, nullptr, nullptr, nullptr,
                                        D, D, 3 * D, D / 64, 1.0f);

    dim3 gt(N / 64, D / 64);
    transpose_f16_k<<<gt, 256, 0, stream>>>(V, VT, N, 3 * D);

    // S = Q @ K^T * (1/32), lower-triangle blocks only
    dim3 gsd(N / 256, N / 256);      // 16 x 16, bj>bi early-out
    gs_f<<<gsd, 512, 131072, stream>>>(Q, K, SP, nullptr, nullptr, nullptr,
                                       3 * D, 3 * D, N, D / 64, 0.03125f);

    // single sweep: P' = keep * exp(S), L[row] = sum exp(S)
    softdrop_k<<<N, 256, 0, stream>>>(SP, Lr, N);

    // PV on the 8-phase engine: balanced causal split-K (chunks of <=16 BK-tiles)
    dim3 go(40, D / 256);            // 160 blocks
    gpv_f<<<go, 512, 131072, stream>>>(SP, VT, out, P1, P2, P3,
                                       N, N, D, 0, 1.0f);

    // merge split-K partials + apply 1/(0.9*L) row scaling
    pv_scale_reduce_k<<<N, 256, 0, stream>>>(out, P1, P2, P3, Lr);
}

// Round 10
// 145.470 us; speedup vs baseline: 1.1435x; 1.0418x over previous
//
#include <hip/hip_runtime.h>
#include <hip/hip_fp16.h>

// ---------- types ----------
typedef __attribute__((ext_vector_type(8))) _Float16 f16x8;
typedef __attribute__((ext_vector_type(4))) float f32x4;

typedef const __attribute__((address_space(1))) void gas_void;
typedef __attribute__((address_space(3))) void las_void;
typedef __attribute__((address_space(3))) const __half las_chalf;

// asm ds_read_b128: opaque to the compiler's waitcnt pass (we manage lgkmcnt)
__device__ __forceinline__ f16x8 ldsr(const __half* p) {
    f16x8 r;
    asm volatile("ds_read_b128 %0, %1" : "=v"(r) : "v"((las_chalf*)p));
    return r;
}

// ---------- all input casts f32 -> f16 in one dispatch (grid 3584) ----------
__global__ __launch_bounds__(256) void cast_all_k(const float* __restrict__ x,
                                                  const float* __restrict__ wq,
                                                  const float* __restrict__ wk,
                                                  const float* __restrict__ wv,
                                                  __half* __restrict__ xb,
                                                  __half* __restrict__ wqkv) {
    const int b = blockIdx.x;
    const float* src;
    __half* dst;
    size_t i;
    if (b < 2048) {
        src = x; dst = xb;
        i = ((size_t)b * 256 + threadIdx.x) * 8;
    } else {
        const int w = (b - 2048) >> 9;
        src = w == 0 ? wq : (w == 1 ? wk : wv);
        dst = wqkv + (size_t)w * 1048576;
        i = (((size_t)((b - 2048) & 511)) * 256 + threadIdx.x) * 8;
    }
    float4 a = *(const float4*)(src + i);
    float4 c = *(const float4*)(src + i + 4);
    __half2 h[4] = { __floats2half2_rn(a.x, a.y), __floats2half2_rn(a.z, a.w),
                     __floats2half2_rn(c.x, c.y), __floats2half2_rn(c.z, c.w) };
    *(int4*)(dst + i) = *(int4*)h;
}

// ============================================================================
// 256x256 8-phase GEMM engine (T1+T2+T3+T4+T5), C = scale * A @ B^T, f16 in.
// 8 waves (2M x 4N), BK=64, LDS 128KB dynamic: [buf(2)][mat(2)][256][64] f16.
// MODE 0 (QKVT): 1D grid 192, XCD-swizzled. sw<128: QK proj (C=pC, ld 2048);
//                sw>=128: VT = wv @ x^T (C=pC2, ld 4096). lda=ldb=1024.
// MODE 1 (S)   : 1D grid 136, XCD-swizzled triangular decode. ld 2048/2048/4096.
// MODE 2 (PV)  : 1D grid 160, XCD-swizzled; balanced causal split-K; chunk 0
//                writes out (rows<1024 scaled by 1/(0.9 L)), chunks 1-3 -> P1..P3.
// ============================================================================
template <int MODE>
__global__ __launch_bounds__(512, 2)
void gemm256(const __half* __restrict__ pA, const __half* __restrict__ pB,
             void* __restrict__ pC, void* __restrict__ pC2,
             float* __restrict__ P1, float* __restrict__ P2, float* __restrict__ P3,
             const float* __restrict__ Lr) {
    constexpr int LDA = (MODE == 0) ? 1024 : (MODE == 1 ? 2048 : 4096);
    constexpr int LDB = (MODE == 0) ? 1024 : (MODE == 1 ? 2048 : 4096);
    constexpr float SCALE = (MODE == 1) ? 0.03125f : 1.0f;

    int bi, bj, c = 0, k_lo = 0, NT = 16;
    bool isVT = false;
    if constexpr (MODE == 0) {
        const int id = blockIdx.x;
        const int sw = (id & 7) * 24 + (id >> 3);          // 192 = 8*24, bijective
        if (sw < 128) { bi = sw >> 3; bj = sw & 7; }
        else          { int s2 = sw - 128; bi = s2 >> 4; bj = s2 & 15; isVT = true; }
    } else if constexpr (MODE == 1) {
        const int id = blockIdx.x;
        const int sw = (id & 7) * 17 + (id >> 3);          // 136 = 8*17
        int b = (int)((sqrtf(8.0f * sw + 1.0f) - 1.0f) * 0.5f);
        while ((b + 1) * (b + 2) / 2 <= sw) ++b;
        while (b * (b + 1) / 2 > sw) --b;
        bi = b; bj = sw - b * (b + 1) / 2;
    } else {
        const int id = blockIdx.x;
        const int sw = (id & 7) * 20 + (id >> 3);          // 160 = 8*20
        bj = sw / 40;
        const int x = sw - 40 * bj;
        if (x < 4)       { bi = x;                    c = 0; }
        else if (x < 12) { bi = 4  + ((x - 4) >> 1);  c = (x - 4) & 1; }
        else if (x < 24) { bi = 8  + (x - 12) / 3;    c = (x - 12) % 3; }
        else             { bi = 12 + ((x - 24) >> 2); c = (x - 24) & 3; }
        const int full = 4 * (bi + 1);
        k_lo = c * 16;
        NT = min(full - k_lo, 16);
    }

    const __half* A = pA;
    const __half* B = pB;
    if constexpr (MODE == 0) {
        if (isVT) { A = pB + 2097152; B = pA; }   // A = wv (rows 2048.. of wqkv), B = x
    }

    const int brow = bi * 256, bcol = bj * 256;
    const int tid = threadIdx.x;
    const int lane = tid & 63, wid = tid >> 6;
    const int wm = wid >> 2, wn = wid & 3;
    const int lane15 = lane & 15;
    const int kxor = (lane & 7) << 3;
    const int g16 = (lane >> 4) << 3;

    extern __shared__ __half smem[];  // [2][2][256*64]

    const int srow = (wid << 3) + (lane >> 3);                 // 0..63
    const int scol = ((lane & 7) ^ ((lane >> 3) & 7)) << 3;    // swizzled source col

    auto stage_half = [&](const __half* G, int ldg, int growbase, int kt, int buf, int mat, int half) {
        const __half* src = G + (size_t)(growbase + half * 128 + srow) * ldg + kt * 64 + scol;
        __half* dst = &smem[buf * 32768 + mat * 16384 + (half * 128 + (wid << 3)) * 64];
        __builtin_amdgcn_global_load_lds((gas_void*)src, (las_void*)dst, 16, 0, 0);
        __builtin_amdgcn_global_load_lds((gas_void*)(src + (size_t)64 * ldg),
                                         (las_void*)(dst + 64 * 64), 16, 0, 0);
    };

    f32x4 acc[8][4] = {};
    f16x8 bfrag[2][4];

    // prologue: tile k_lo {Ba,Bb,Aa,Ab} + tile k_lo+1 {Ba,Bb}
    stage_half(B, LDB, bcol, k_lo, 0, 1, 0);
    stage_half(B, LDB, bcol, k_lo, 0, 1, 1);
    stage_half(A, LDA, brow, k_lo, 0, 0, 0);
    stage_half(A, LDA, brow, k_lo, 0, 0, 1);
    if (NT > 1) {
        stage_half(B, LDB, bcol, k_lo + 1, 1, 1, 0);
        stage_half(B, LDB, bcol, k_lo + 1, 1, 1, 1);
    }

    for (int Tr = 0; Tr < NT; ++Tr) {
        const int Ta = k_lo + Tr;
        const int buf = Tr & 1;
        const __half* Abase = &smem[buf * 32768 + (wm * 128 + lane15) * 64];
        const __half* Bbase = &smem[buf * 32768 + 16384 + (wn * 64 + lane15) * 64];

        // ---- phase 0 ----
        if (Tr < NT - 1) asm volatile("s_waitcnt vmcnt(4)" ::: "memory");
        else             asm volatile("s_waitcnt vmcnt(0)" ::: "memory");
        __builtin_amdgcn_s_barrier();   // tile Tr fully resident for all waves

        {
#pragma unroll
            for (int kk = 0; kk < 2; ++kk)
#pragma unroll
                for (int n = 0; n < 4; ++n)
                    bfrag[kk][n] = ldsr(Bbase + (n * 16) * 64 + ((kk * 32 + g16) ^ kxor));
            f16x8 af[2][2];
#pragma unroll
            for (int mi = 0; mi < 2; ++mi)
#pragma unroll
                for (int kk = 0; kk < 2; ++kk)
                    af[mi][kk] = ldsr(Abase + (mi * 16) * 64 + ((kk * 32 + g16) ^ kxor));
            if (Tr + 1 < NT) stage_half(A, LDA, brow, Ta + 1, buf ^ 1, 0, 0);
            asm volatile("s_waitcnt lgkmcnt(0)" ::: "memory");
            __builtin_amdgcn_sched_barrier(0);
            __builtin_amdgcn_s_setprio(1);
#pragma unroll
            for (int mi = 0; mi < 2; ++mi)
#pragma unroll
                for (int n = 0; n < 4; ++n)
#pragma unroll
                    for (int kk = 0; kk < 2; ++kk)
                        acc[mi][n] = __builtin_amdgcn_mfma_f32_16x16x32_f16(
                            af[mi][kk], bfrag[kk][n], acc[mi][n], 0, 0, 0);
            __builtin_amdgcn_s_setprio(0);
            __builtin_amdgcn_s_barrier();
        }

        // ---- phases 1..3 ----
#pragma unroll
        for (int p = 1; p < 4; ++p) {
            f16x8 af[2][2];
#pragma unroll
            for (int mi = 0; mi < 2; ++mi)
#pragma unroll
                for (int kk = 0; kk < 2; ++kk)
                    af[mi][kk] = ldsr(Abase + ((2 * p + mi) * 16) * 64 + ((kk * 32 + g16) ^ kxor));
            if (p == 1)      { if (Tr + 1 < NT) stage_half(A, LDA, brow, Ta + 1, buf ^ 1, 0, 1); }
            else if (p == 2) { if (Tr + 2 < NT) stage_half(B, LDB, bcol, Ta + 2, buf, 1, 0); }
            else             { if (Tr + 2 < NT) stage_half(B, LDB, bcol, Ta + 2, buf, 1, 1); }
            asm volatile("s_waitcnt lgkmcnt(0)" ::: "memory");
            __builtin_amdgcn_sched_barrier(0);
            __builtin_amdgcn_s_setprio(1);
#pragma unroll
            for (int mi = 0; mi < 2; ++mi)
#pragma unroll
                for (int n = 0; n < 4; ++n)
#pragma unroll
                    for (int kk = 0; kk < 2; ++kk)
                        acc[2 * p + mi][n] = __builtin_amdgcn_mfma_f32_16x16x32_f16(
                            af[mi][kk], bfrag[kk][n], acc[2 * p + mi][n], 0, 0, 0);
            __builtin_amdgcn_s_setprio(0);
            __builtin_amdgcn_s_barrier();
        }
    }

    // ---- epilogue ----
    const int r0 = (lane >> 4) << 2;
    if constexpr (MODE == 2) {
        float* Ct = (float*)pC;
        if (c == 1) Ct = P1; else if (c == 2) Ct = P2; else if (c == 3) Ct = P3;
        const bool doScale = (c == 0) && (bi < 4);   // complete rows: scale here
#pragma unroll
        for (int m = 0; m < 8; ++m) {
#pragma unroll
            for (int r = 0; r < 4; ++r) {
                const int row = brow + wm * 128 + m * 16 + r0 + r;
                const float inv = doScale ? 1.0f / (0.9f * Lr[row]) : 1.0f;
#pragma unroll
                for (int n = 0; n < 4; ++n) {
                    const int col = bcol + wn * 64 + n * 16 + lane15;
                    Ct[(size_t)row * 1024 + col] = acc[m][n][r] * inv;
                }
            }
        }
    } else {
        __half* Ct = (__half*)pC;
        int ldc = (MODE == 1) ? 4096 : 2048;
        if constexpr (MODE == 0) {
            if (isVT) { Ct = (__half*)pC2; ldc = 4096; }
        }
#pragma unroll
        for (int m = 0; m < 8; ++m) {
#pragma unroll
            for (int n = 0; n < 4; ++n) {
                const int col = bcol + wn * 64 + n * 16 + lane15;
#pragma unroll
                for (int r = 0; r < 4; ++r) {
                    const int row = brow + wm * 128 + m * 16 + r0 + r;
                    Ct[(size_t)row * ldc + col] = __float2half(acc[m][n][r] * SCALE);
                }
            }
        }
    }
}

// ---------- split-K merge + deferred softmax scaling (rows >= 1024 only) ----------
__global__ __launch_bounds__(256) void pv_scale_reduce_k(float* __restrict__ out,
                                                         const float* __restrict__ P1,
                                                         const float* __restrict__ P2,
                                                         const float* __restrict__ P3,
                                                         const float* __restrict__ L) {
    const int row = 1024 + blockIdx.x;
    const float inv = 1.0f / (0.9f * L[row]);
    const size_t o = (size_t)row * 1024 + threadIdx.x * 4;
    float4 s = *(float4*)(out + o);
    float4 a = *(const float4*)(P1 + o);
    s.x += a.x; s.y += a.y; s.z += a.z; s.w += a.w;
    if (row >= 2048) {
        float4 b = *(const float4*)(P2 + o);
        s.x += b.x; s.y += b.y; s.z += b.z; s.w += b.w;
    }
    if (row >= 3072) {
        float4 d = *(const float4*)(P3 + o);
        s.x += d.x; s.y += d.y; s.z += d.z; s.w += d.w;
    }
    s.x *= inv; s.y *= inv; s.z *= inv; s.w *= inv;
    *(float4*)(out + o) = s;
}

// ---------- threefry2x32, JAX PARTITIONABLE variant ----------
__device__ __forceinline__ uint32_t rotl32(uint32_t x, int d) { return (x << d) | (x >> (32 - d)); }

__device__ __forceinline__ bool keep_bit(uint32_t flat) {
    uint32_t x0 = 0u;
    uint32_t x1 = flat;
    const uint32_t ks0 = 0u, ks1 = 42u, ks2 = 0u ^ 42u ^ 0x1BD11BDAu;
    x0 += ks0; x1 += ks1;
#define TFR(r) { x0 += x1; x1 = rotl32(x1, r); x1 ^= x0; }
    TFR(13) TFR(15) TFR(26) TFR(6)   x0 += ks1; x1 += ks2 + 1u;
    TFR(17) TFR(29) TFR(16) TFR(24)  x0 += ks2; x1 += ks0 + 2u;
    TFR(13) TFR(15) TFR(26) TFR(6)   x0 += ks0; x1 += ks1 + 3u;
    TFR(17) TFR(29) TFR(16) TFR(24)  x0 += ks1; x1 += ks2 + 4u;
    TFR(13) TFR(15) TFR(26) TFR(6)   x0 += ks2; x1 += ks0 + 5u;
#undef TFR
    uint32_t bits = x0 ^ x1;
    float u = __uint_as_float((bits >> 9) | 0x3f800000u) - 1.0f;
    return u < 0.9f;
}

// ---------- single-sweep deferred softmax: P' = keep * exp(S) (M=0), L[row] = sum(exp) ----------
__global__ __launch_bounds__(256) void softdrop_k(__half* __restrict__ SP,
                                                  float* __restrict__ L, int N) {
    const int i = blockIdx.x;
    const int tid = threadIdx.x;
    const int len = i + 1;
    __half* row = SP + (size_t)i * N;

    float l = 0.f;
    const int len8 = len & ~7;
    for (int j = tid * 8; j < len8; j += 2048) {
        int4 pk = *(const int4*)(row + j);
        const __half* hp = (const __half*)&pk;
        __half o8[8];
        const uint32_t base = (uint32_t)i * 4096u + (uint32_t)j;
#pragma unroll
        for (int q = 0; q < 8; ++q) {
            float e = __expf(__half2float(hp[q]));
            l += e;
            o8[q] = keep_bit(base + q) ? __float2half(e) : __float2half(0.0f);
        }
        *(int4*)(row + j) = *(int4*)o8;
    }
    for (int j = len8 + tid; j < len; j += 256) {
        float e = __expf(__half2float(row[j]));
        l += e;
        row[j] = keep_bit((uint32_t)i * 4096u + (uint32_t)j) ? __float2half(e) : __float2half(0.0f);
    }

    for (int off = 1; off < 64; off <<= 1) l += __shfl_xor(l, off);
    __shared__ float ls[4];
    if ((tid & 63) == 0) ls[tid >> 6] = l;
    __syncthreads();
    if (tid == 0) L[i] = ls[0] + ls[1] + ls[2] + ls[3];

    // zero the diagonal band up to the next 256 boundary (PV K-tiles are 256 wide)
    const int zlim = ((i >> 8) << 8) + 256;
    const int za = (len + 7) & ~7;
    for (int j = len + tid; j < min(za, zlim); j += 256) row[j] = __float2half(0.0f);
    const int4 z = {0, 0, 0, 0};
    for (int j = za + tid * 8; j < zlim; j += 2048) *(int4*)(row + j) = z;
}

// ---------- launch ----------
extern "C" void kernel_launch(void* const* d_in, const int* in_sizes, int n_in,
                              void* d_out, int out_size, void* d_ws, size_t ws_size,
                              hipStream_t stream) {
    const float* x  = (const float*)d_in[0];
    const float* wq = (const float*)d_in[1];
    const float* wk = (const float*)d_in[2];
    const float* wv = (const float*)d_in[3];
    float* out = (float*)d_out;
    char* ws = (char*)d_ws;

    const int N = 4096, D = 1024;

    __half* xb   = (__half*)(ws + 0);         // 4096x1024   (8 MB)
    __half* wqkv = (__half*)(ws + 8388608);   // 3072x1024   (6 MB)
    __half* QK   = (__half*)(ws + 14680064);  // 4096x2048   (16 MB), ld=2048
    __half* VT   = (__half*)(ws + 31457280);  // 1024x4096   (8 MB),  ld=4096
    __half* SP   = (__half*)(ws + 48234496);  // 4096x4096   (32 MB)
    float*  Lr   = (float*)(ws + 81788928);   // 4096 f32    (16 KB)

    // split-K partials (indexed by absolute row), overlaying dead regions:
    // P1 rows 1024-4095 (12MB) over QK[0..12M); P3 rows 3072-4095 (4MB) over QK tail;
    // P2 rows 2048-4095 (8MB) in the gap between VT end and SP start.
    float* P1 = (float*)(ws + 14680064) - (size_t)1024 * 1024;
    float* P3 = (float*)(ws + 27262976) - (size_t)3072 * 1024;
    float* P2 = (float*)(ws + 39845888) - (size_t)2048 * 1024;

    __half* Q = QK;             // ld = 2048
    __half* K = QK + 1024;

    auto* g0 = gemm256<0>;
    auto* g1 = gemm256<1>;
    auto* g2 = gemm256<2>;
    (void)hipFuncSetAttribute((const void*)g0, hipFuncAttributeMaxDynamicSharedMemorySize, 131072);
    (void)hipFuncSetAttribute((const void*)g1, hipFuncAttributeMaxDynamicSharedMemorySize, 131072);
    (void)hipFuncSetAttribute((const void*)g2, hipFuncAttributeMaxDynamicSharedMemorySize, 131072);

    cast_all_k<<<3584, 256, 0, stream>>>(x, wq, wk, wv, xb, wqkv);

    // QK projection + native V^T (= wv @ x^T), one dispatch, 192 blocks
    g0<<<192, 512, 131072, stream>>>(xb, wqkv, QK, VT, nullptr, nullptr, nullptr, nullptr);

    // S = Q @ K^T * (1/32), triangular 136 blocks
    g1<<<136, 512, 131072, stream>>>(Q, K, SP, nullptr, nullptr, nullptr, nullptr, nullptr);

    // single sweep: P' = keep * exp(S), L[row] = sum exp(S)
    softdrop_k<<<N, 256, 0, stream>>>(SP, Lr, N);

    // PV: balanced causal split-K, 160 blocks; rows<1024 scaled in-epilogue
    g2<<<160, 512, 131072, stream>>>(SP, VT, out, nullptr, P1, P2, P3, Lr);

    // merge split-K partials + apply 1/(0.9*L) for rows >= 1024
    pv_scale_reduce_k<<<3072, 256, 0, stream>>>(out, P1, P2, P3, Lr);
}